// Round 14
// baseline (92.002 us; speedup 1.0000x reference)
//
#include <hip/hip_runtime.h>
#include <hip/hip_bf16.h>
#include <stdint.h>

#define B_ 8
#define C_ 2048
#define E_ 1024
#define H_ 128
#define M_ (B_*C_)      // 16384 rows total
#define SLOTS_B 144     // chunks per batch: sum_j ceil((j+1)/4), j<32

typedef __attribute__((ext_vector_type(8))) short bf16x8;
typedef __attribute__((ext_vector_type(4))) float f32x4;

__device__ __forceinline__ unsigned short f2bf(float f) {
    union { float f; unsigned int u; } v; v.f = f;
    unsigned int u = v.u;
    u += 0x7fff + ((u >> 16) & 1);   // RNE
    return (unsigned short)(u >> 16);
}
__device__ __forceinline__ float bf2f(unsigned short u) {
    union { unsigned int i; float f; } v; v.i = ((unsigned int)u) << 16; return v.f;
}
// pack two floats -> two bf16 (round-half-up) in ONE v_perm + 2 adds
__device__ __forceinline__ unsigned int pack2bf(float lo, float hi) {
    union { float f; unsigned int u; } a, b; a.f = lo; b.f = hi;
    return __builtin_amdgcn_perm(b.u + 0x8000u, a.u + 0x8000u, 0x07060302);
}

#define GLOAD_LDS16(g, l) \
    __builtin_amdgcn_global_load_lds((const __attribute__((address_space(1))) void*)(g), \
                                     (__attribute__((address_space(3))) void*)(l), 16, 0, 0)

// ---------------- W transpose+convert: (E,H) f32 -> (H,E) bf16, x3 ----------
__global__ __launch_bounds__(256) void wt_kernel(const float* __restrict__ Wq,
                                                 const float* __restrict__ Wk,
                                                 const float* __restrict__ Wv,
                                                 unsigned short* __restrict__ WT) {
    int z = blockIdx.y;
    const float* W = (z == 0) ? Wq : (z == 1) ? Wk : Wv;
    unsigned short* o = WT + (size_t)z * H_ * E_;
    int idx = blockIdx.x * 256 + threadIdx.x;   // over H*E = 131072
    int e = idx & (E_ - 1), h = idx >> 10;
    o[(size_t)h * E_ + e] = f2bf(W[(size_t)e * H_ + h]);
}

// ------ QKV projection: BM=64 BN=128, T4 counted-vmcnt raw-barrier pipeline --
// A: f32 via global_load_lds, 3 buffers, staged 2 steps ahead (slot-swizzled).
// B: bf16 via global_load_lds, 2 buffers, staged 1 step ahead (granule-swz).
// Per body: 4 B-gloads + 4 A-gloads; top wait = vmcnt(4) (newest A group flies).
#define MF(a, b, c) __builtin_amdgcn_mfma_f32_16x16x32_bf16((a), (b), (c), 0, 0, 0)

__global__ __launch_bounds__(256) void proj_kernel(const float* __restrict__ x,
                                                   const unsigned short* __restrict__ WT,
                                                   unsigned short* __restrict__ QKV) {
    __shared__ __align__(16) float Asf[3][64][64];            // 48 KB, 16B-slot swz
    __shared__ __align__(16) unsigned short Bs[2][128][64];   // 32 KB, granule swz

    const int tid = threadIdx.x;
    const int wid = tid >> 6, lane = tid & 63;
    const int lrow = lane & 15, lq = lane >> 4;
    const int wr = wid >> 1, wc = wid & 1;       // wave tile: rows wr*32, cols wc*64
    const int row0 = blockIdx.x * 64;
    const int w = blockIdx.y;
    const unsigned short* wt = WT + (size_t)w * H_ * E_;

    const int srow = tid >> 4;          // A staging: row within shot (0..15)
    const int slotL = tid & 15;         // LDS 16B-slot within 64-float row

    auto ASTAGE = [&](int buf, int t) { // 4 gloads/thread, linear dest
#pragma unroll
        for (int s = 0; s < 4; ++s) {
            int row = s * 16 + srow;
            const float* src = x + (size_t)(row0 + row) * E_ + t * 64
                             + ((slotL ^ (row & 7)) * 4);
            GLOAD_LDS16(src, (char*)&Asf[buf][0][0] + s * 4096 + tid * 16);
        }
    };
    auto BSTAGE = [&](int buf, int t) { // 4 gloads/thread, linear dest
#pragma unroll
        for (int s = 0; s < 4; ++s) {
            int brow = s * 32 + (tid >> 3);
            int bg = (tid & 7) ^ (brow & 7);
            GLOAD_LDS16(wt + (size_t)brow * E_ + t * 64 + bg * 8,
                        (char*)&Bs[buf][0][0] + s * 4096 + tid * 16);
        }
    };

    f32x4 acc[2][4];
#pragma unroll
    for (int mi = 0; mi < 2; ++mi)
#pragma unroll
        for (int ni = 0; ni < 4; ++ni) acc[mi][ni] = (f32x4){0.f, 0.f, 0.f, 0.f};

    // prologue: B(0); A(0); A(1)  (newest 4 = A(1) stays in flight at first top)
    BSTAGE(0, 0);
    ASTAGE(0, 0);
    ASTAGE(1, 1);

    int a0 = 0, a1 = 1, a2 = 2;         // A buffer rotation
    for (int t = 0; t < 16; ++t) {
        const int bb = t & 1;
        // tile-t A (issued t-2) and B (issued t-1) retired; A(t+1) may fly
        asm volatile("s_waitcnt vmcnt(4)\n\ts_barrier" ::: "memory");
        __builtin_amdgcn_sched_barrier(0);
        BSTAGE(bb ^ 1, min(t + 1, 15)); // 1-step-ahead B (dummy on last)
        ASTAGE(a2, min(t + 2, 15));     // 2-step-ahead A (dummy on last two)

        // compute tile t from Asf[a0] (f32 + convert) and Bs[bb]
#pragma unroll
        for (int ks = 0; ks < 2; ++ks) {
            const int g2 = (ks * 4 + lq) * 2;
            bf16x8 af[2], bfr[4];
#pragma unroll
            for (int mi = 0; mi < 2; ++mi) {
                int row = wr * 32 + mi * 16 + lrow;
                int m7 = row & 7;
                f32x4 f0 = *(const f32x4*)&Asf[a0][row][(g2 ^ m7) * 4];
                f32x4 f1 = *(const f32x4*)&Asf[a0][row][((g2 + 1) ^ m7) * 4];
                union { unsigned int u[4]; bf16x8 v; } pk;
                pk.u[0] = pack2bf(f0[0], f0[1]);
                pk.u[1] = pack2bf(f0[2], f0[3]);
                pk.u[2] = pack2bf(f1[0], f1[1]);
                pk.u[3] = pack2bf(f1[2], f1[3]);
                af[mi] = pk.v;
            }
#pragma unroll
            for (int ni = 0; ni < 4; ++ni) {
                int rb = wc * 64 + ni * 16 + lrow;
                bfr[ni] = *(const bf16x8*)&Bs[bb][rb][((ks * 4 + lq) ^ (rb & 7)) * 8];
            }
#pragma unroll
            for (int mi = 0; mi < 2; ++mi)
#pragma unroll
                for (int ni = 0; ni < 4; ++ni)
                    acc[mi][ni] = MF(af[mi], bfr[ni], acc[mi][ni]);
        }
        int tmp = a0; a0 = a1; a1 = a2; a2 = tmp;
    }

    // epilogue: Q (scaled 1/32), K row-major; V transposed [b][h][c]
    if (w < 2) {
        const float qs = (w == 0) ? 0.03125f : 1.0f;   // fold 1/sqrt(E) into Q
        unsigned short* outp = QKV + (size_t)w * M_ * H_;
#pragma unroll
        for (int mi = 0; mi < 2; ++mi) {
            int r0 = row0 + wr * 32 + mi * 16 + lq * 4;
#pragma unroll
            for (int ni = 0; ni < 4; ++ni) {
                int col = wc * 64 + ni * 16 + lrow;
#pragma unroll
                for (int r = 0; r < 4; ++r)
                    outp[(size_t)(r0 + r) * H_ + col] = f2bf(acc[mi][ni][r] * qs);
            }
        }
    } else {
        unsigned short* vt = QKV + (size_t)2 * M_ * H_;
        int b = row0 / C_;
        int cbase = row0 % C_;
#pragma unroll
        for (int mi = 0; mi < 2; ++mi) {
            int c0 = cbase + wr * 32 + mi * 16 + lq * 4;
#pragma unroll
            for (int ni = 0; ni < 4; ++ni) {
                int h = wc * 64 + ni * 16 + lrow;
                __align__(8) unsigned short p[4] = {f2bf(acc[mi][ni][0]), f2bf(acc[mi][ni][1]),
                                                    f2bf(acc[mi][ni][2]), f2bf(acc[mi][ni][3])};
                *(uint2*)&vt[((size_t)b * H_ + h) * C_ + c0] = *(const uint2*)p;
            }
        }
    }
}

// ---------------- split-KV flash attention, swapped-QK lane-local softmax ----
// grid (B, 144): blockIdx.x = batch -> XCD = b.
__global__ __launch_bounds__(256) void attn_kernel(const unsigned short* __restrict__ QKV,
                                                   unsigned short* __restrict__ PO,
                                                   float* __restrict__ ML,
                                                   float* __restrict__ out) {
    __shared__ __align__(16) unsigned short Ks[2][64][128];
    __shared__ __align__(16) unsigned short Vt[2][128][64];

    const unsigned short* Q  = QKV;
    const unsigned short* K  = QKV + (size_t)M_ * H_;
    const unsigned short* VT = QKV + (size_t)2 * M_ * H_;

    const int tid = threadIdx.x, wid = tid >> 6, lane = tid & 63;
    const int lrow = lane & 15, lq = lane >> 4, lk = lq * 8;
    const int b = blockIdx.x;
    const int rr = blockIdx.y;

    int j = 0;
#pragma unroll
    for (int jj = 1; jj < 32; ++jj) {
        int q = jj >> 2, s = jj & 3;
        if (jj + 2 * q * (q - 1) + s * q <= rr) j = jj;
    }
    const int qj = j >> 2, sj = j & 3;
    const int Cj = j + 2 * qj * (qj - 1) + sj * qj;
    const int c = rr - Cj;
    const int nch = qj + 1;
    const int t0 = c * 4;
    const int t1 = min(t0 + 4, j + 1);

    const int q0w = j * 64 + wid * 16;
    const unsigned short* Kb  = K  + (size_t)b * C_ * H_;
    const unsigned short* VTb = VT + (size_t)b * H_ * C_;
    const int qabs = q0w + lrow;        // this lane's q row (softmax space)

    const int krow = tid >> 4, kg = tid & 15;
    const int vrow = tid >> 3, vg = tid & 7;

    bf16x8 qf[4];
#pragma unroll
    for (int kf = 0; kf < 4; ++kf)
        qf[kf] = *(const bf16x8*)&Q[((size_t)b * C_ + q0w + lrow) * H_ + kf * 32 + lk];

    f32x4 o[8];
#pragma unroll
    for (int nf = 0; nf < 8; ++nf) o[nf] = (f32x4){0.f, 0.f, 0.f, 0.f};
    float m = -INFINITY, l = 0.f;       // scalar state for q = qabs

    auto STAGE = [&](int buf, int t) {
        const int kv0 = t * 64;
#pragma unroll
        for (int s = 0; s < 4; ++s) {
            int r = s * 16 + krow;      // LDS row
            int prow = ((r & 0x10) << 1) | ((r & 0x0C) << 1) | ((r & 0x20) >> 3) | (r & 3);
            GLOAD_LDS16(&Kb[(size_t)(kv0 + prow) * H_ + ((kg ^ (r & 15)) * 8)],
                        (char*)&Ks[buf][0][0] + s * 4096 + tid * 16);
        }
#pragma unroll
        for (int s = 0; s < 4; ++s) {
            int h = s * 32 + vrow;
            GLOAD_LDS16(&VTb[(size_t)h * C_ + kv0 + ((vg ^ (h & 7)) * 8)],
                        (char*)&Vt[buf][0][0] + s * 4096 + tid * 16);
        }
    };

    STAGE(0, t0);

    for (int t = t0; t < t1; ++t) {
        const int cur = (t - t0) & 1;
        __syncthreads();
        if (t + 1 < t1) STAGE(cur ^ 1, t + 1);

        const int kv0 = t * 64;
        f32x4 s[4];
        __builtin_amdgcn_s_setprio(1);
#pragma unroll
        for (int nf = 0; nf < 4; ++nf) {
            s[nf] = (f32x4){0.f, 0.f, 0.f, 0.f};
            const int rk = nf * 16 + lrow;
#pragma unroll
            for (int kf = 0; kf < 4; ++kf) {
                bf16x8 kb = *(const bf16x8*)&Ks[cur][rk][((kf * 4 + lq) ^ (rk & 15)) * 8];
                s[nf] = __builtin_amdgcn_mfma_f32_16x16x32_bf16(kb, qf[kf], s[nf], 0, 0, 0); // SWAPPED
            }
        }
        __builtin_amdgcn_s_setprio(0);
        bf16x8 vb[8][2];
#pragma unroll
        for (int nf = 0; nf < 8; ++nf) {
            const int h = nf * 16 + lrow;
#pragma unroll
            for (int kf2 = 0; kf2 < 2; ++kf2)
                vb[nf][kf2] = *(const bf16x8*)&Vt[cur][h][((kf2 * 4 + lq) ^ (h & 7)) * 8];
        }

        // lane holds S[kv][q=qabs]; kv = kv0 + (nf&1)*32 + lq*8 + (nf>>1)*4 + r
        if (t == j) {
#pragma unroll
            for (int nf = 0; nf < 4; ++nf) {
                int kvb = kv0 + ((nf & 1) << 5) + (lq << 3) + ((nf >> 1) << 2);
#pragma unroll
                for (int r = 0; r < 4; ++r)
                    if (kvb + r > qabs) s[nf][r] = -INFINITY;
            }
        }
        float mt = s[0][0];
#pragma unroll
        for (int nf = 0; nf < 4; ++nf)
#pragma unroll
            for (int r = 0; r < 4; ++r) mt = fmaxf(mt, s[nf][r]);
        mt = fmaxf(mt, __shfl_xor(mt, 16));
        mt = fmaxf(mt, __shfl_xor(mt, 32));

        float mn = fmaxf(m, mt);
        float corr = __expf(m - mn);
        m = mn;

        float p[4][4];
        float ps = 0.f;
#pragma unroll
        for (int nf = 0; nf < 4; ++nf)
#pragma unroll
            for (int r = 0; r < 4; ++r) {
                float e = __expf(s[nf][r] - mn);
                p[nf][r] = e;
                ps += e;
            }
        ps += __shfl_xor(ps, 16);
        ps += __shfl_xor(ps, 32);
        l = l * corr + ps;

        float corr4[4];
#pragma unroll
        for (int r = 0; r < 4; ++r)
            corr4[r] = __shfl(corr, (lane & 48) | (lq * 4 + r));
#pragma unroll
        for (int nf = 0; nf < 8; ++nf)
#pragma unroll
            for (int r = 0; r < 4; ++r) o[nf][r] *= corr4[r];

        bf16x8 pa[2];
#pragma unroll
        for (int kf2 = 0; kf2 < 2; ++kf2) {
            union { unsigned int u[4]; bf16x8 v; } pk;
            pk.u[0] = pack2bf(p[kf2][0],     p[kf2][1]);
            pk.u[1] = pack2bf(p[kf2][2],     p[kf2][3]);
            pk.u[2] = pack2bf(p[kf2 + 2][0], p[kf2 + 2][1]);
            pk.u[3] = pack2bf(p[kf2 + 2][2], p[kf2 + 2][3]);
            pa[kf2] = pk.v;
        }
        __builtin_amdgcn_s_setprio(1);
#pragma unroll
        for (int nf = 0; nf < 8; ++nf)
#pragma unroll
            for (int kf2 = 0; kf2 < 2; ++kf2)
                o[nf] = __builtin_amdgcn_mfma_f32_16x16x32_bf16(pa[kf2], vb[nf][kf2], o[nf], 0, 0, 0);
        __builtin_amdgcn_s_setprio(0);
    }

    float l4[4], m4[4];
#pragma unroll
    for (int r = 0; r < 4; ++r) {
        l4[r] = __shfl(l, (lane & 48) | (lq * 4 + r));
        m4[r] = __shfl(m, (lane & 48) | (lq * 4 + r));
    }
    const int qrow0 = q0w + lq * 4;

    if (nch == 1) {
#pragma unroll
        for (int nf = 0; nf < 8; ++nf) {
            int col = nf * 16 + lrow;
#pragma unroll
            for (int r = 0; r < 4; ++r)
                out[((size_t)b * C_ + qrow0 + r) * H_ + col] = o[nf][r] / l4[r];
        }
    } else {
        const int slot = b * SLOTS_B + rr;
        unsigned short* po = PO + (size_t)slot * 64 * 128;
        const int rl0 = wid * 16 + lq * 4;
#pragma unroll
        for (int nf = 0; nf < 8; ++nf) {
            int col = nf * 16 + lrow;
#pragma unroll
            for (int r = 0; r < 4; ++r)
                po[(size_t)(rl0 + r) * 128 + col] = f2bf(o[nf][r]);
        }
        if (lrow == 0) {
            float* ml = ML + (size_t)slot * 128;
#pragma unroll
            for (int r = 0; r < 4; ++r) {
                ml[rl0 + r] = m4[r];
                ml[64 + rl0 + r] = l4[r];
            }
        }
    }
}

// ---------------- combine partials for j >= 4 --------------------------------
__global__ __launch_bounds__(256) void combine_kernel(const unsigned short* __restrict__ PO,
                                                      const float* __restrict__ ML,
                                                      float* __restrict__ out) {
    const int j = blockIdx.x + 4;
    const int b = blockIdx.y;
    const int q = j >> 2, s = j & 3;
    const int Cj = j + 2 * q * (q - 1) + s * q;
    const int nch = q + 1;
    const int base = b * SLOTS_B + Cj;
    const int row = threadIdx.x >> 2;
    const int colg = (threadIdx.x & 3) * 32;

    float mstar = -INFINITY;
    for (int c = 0; c < nch; ++c)
        mstar = fmaxf(mstar, ML[(size_t)(base + c) * 128 + row]);

    float denom = 0.f;
    float acc[32];
#pragma unroll
    for (int i = 0; i < 32; ++i) acc[i] = 0.f;

    for (int c = 0; c < nch; ++c) {
        float mc = ML[(size_t)(base + c) * 128 + row];
        float lc = ML[(size_t)(base + c) * 128 + 64 + row];
        float w = __expf(mc - mstar);
        denom += w * lc;
        const unsigned short* p = PO + (size_t)(base + c) * 64 * 128 + (size_t)row * 128 + colg;
#pragma unroll
        for (int k = 0; k < 4; ++k) {
            bf16x8 v = *(const bf16x8*)&p[k * 8];
#pragma unroll
            for (int e = 0; e < 8; ++e)
                acc[k * 8 + e] += w * bf2f(((unsigned short*)&v)[e]);
        }
    }
    float inv = 1.f / denom;
    float* op = out + ((size_t)b * C_ + j * 64 + row) * H_ + colg;
#pragma unroll
    for (int k = 0; k < 8; ++k) {
        float4 st = {acc[k * 4] * inv, acc[k * 4 + 1] * inv, acc[k * 4 + 2] * inv, acc[k * 4 + 3] * inv};
        *(float4*)&op[k * 4] = st;
    }
}

extern "C" void kernel_launch(void* const* d_in, const int* in_sizes, int n_in,
                              void* d_out, int out_size, void* d_ws, size_t ws_size,
                              hipStream_t stream) {
    const float* x  = (const float*)d_in[0];
    const float* Wq = (const float*)d_in[1];
    const float* Wk = (const float*)d_in[2];
    const float* Wv = (const float*)d_in[3];
    float* out = (float*)d_out;

    unsigned short* WT  = (unsigned short*)d_ws;                       // 768 KB (H x E row-major, x3)
    unsigned short* QKV = WT + (size_t)3 * H_ * E_;                    // 12 MB (Q, K, V^T)
    unsigned short* PO  = QKV + (size_t)3 * M_ * H_;                   // 18 MB partial O
    float*          ML  = (float*)(PO + (size_t)8 * SLOTS_B * 64 * 128); // 576 KB m,l

    wt_kernel<<<dim3(H_ * E_ / 256, 3), 256, 0, stream>>>(Wq, Wk, Wv, WT);
    proj_kernel<<<dim3(M_ / 64, 3), 256, 0, stream>>>(x, WT, QKV);
    attn_kernel<<<dim3(B_, SLOTS_B), 256, 0, stream>>>(QKV, PO, ML, out);
    combine_kernel<<<dim3(28, B_), 256, 0, stream>>>(PO, ML, out);
}

// Round 15
// 71.980 us; speedup vs baseline: 1.2781x; 1.2781x over previous
//
#include <hip/hip_runtime.h>
#include <hip/hip_bf16.h>
#include <stdint.h>

#define B_ 8
#define C_ 2048
#define E_ 1024
#define H_ 128
#define M_ (B_*C_)      // 16384 rows total
#define SLOTS_B 144     // chunks per batch: sum_j ceil((j+1)/4), j<32

typedef __attribute__((ext_vector_type(8))) short bf16x8;
typedef __attribute__((ext_vector_type(4))) float f32x4;

__device__ __forceinline__ unsigned short f2bf(float f) {
    union { float f; unsigned int u; } v; v.f = f;
    unsigned int u = v.u;
    u += 0x7fff + ((u >> 16) & 1);   // RNE
    return (unsigned short)(u >> 16);
}
__device__ __forceinline__ float bf2f(unsigned short u) {
    union { unsigned int i; float f; } v; v.i = ((unsigned int)u) << 16; return v.f;
}
// pack two floats -> two bf16 (round-half-up) in ONE v_perm + 2 adds
__device__ __forceinline__ unsigned int pack2bf(float lo, float hi) {
    union { float f; unsigned int u; } a, b; a.f = lo; b.f = hi;
    return __builtin_amdgcn_perm(b.u + 0x8000u, a.u + 0x8000u, 0x07060302);
}

#define GLOAD_LDS16(g, l) \
    __builtin_amdgcn_global_load_lds((const __attribute__((address_space(1))) void*)(g), \
                                     (__attribute__((address_space(3))) void*)(l), 16, 0, 0)

// -------- W -> fragment-ordered bf16: WT2[w][g*128 + h] = 16B granule -------
__global__ __launch_bounds__(256) void wt2_kernel(const float* __restrict__ Wq,
                                                  const float* __restrict__ Wk,
                                                  const float* __restrict__ Wv,
                                                  unsigned short* __restrict__ WT2) {
    int z = blockIdx.y;
    const float* W = (z == 0) ? Wq : (z == 1) ? Wk : Wv;
    unsigned short* o = WT2 + (size_t)z * H_ * E_;
    int gid = blockIdx.x * 256 + threadIdx.x;   // over (E_/8)*H_ = 16384 granules
    int g = gid >> 7, h = gid & 127;
    unsigned short t[8];
#pragma unroll
    for (int j = 0; j < 8; ++j)
        t[j] = f2bf(W[(size_t)(g * 8 + j) * H_ + h]);
    *(bf16x8*)&o[(size_t)(g * 128 + h) * 8] = *(const bf16x8*)t;
}

// ------ fused QKV projection: BM=32, x once; A f32 gload_lds 3-buf 2-ahead
// with counted vmcnt(2); B direct global->reg (L2, fragment-ordered WT2).
#define MF(a, b, c) __builtin_amdgcn_mfma_f32_16x16x32_bf16((a), (b), (c), 0, 0, 0)

__global__ __launch_bounds__(256) void proj_kernel(const float* __restrict__ x,
                                                   const unsigned short* __restrict__ WT2,
                                                   unsigned short* __restrict__ QKV) {
    __shared__ __align__(16) float Asf[3][32][64];    // 24 KB, 16B-slot XOR-swz

    const int tid = threadIdx.x;
    const int wid = tid >> 6, lane = tid & 63;
    const int lrow = lane & 15, lq = lane >> 4;
    const int wcol = wid * 32;          // wave's 32-col slice of H=128
    const int row0 = blockIdx.x * 32;
    const unsigned short* wbase = WT2 + (size_t)(lq * 128 + wcol + lrow) * 8;

    // A staging: 8 KB/tile = 2 shots x 256 thr x 16B; exactly 2 gloads/thread
    const int srow = tid >> 4;          // row within shot (0..15)
    const int slotL = tid & 15;         // linear LDS 16B-slot

    auto ASTAGE = [&](int buf, int t) {
#pragma unroll
        for (int s = 0; s < 2; ++s) {
            int row = s * 16 + srow;
            const float* src = x + (size_t)(row0 + row) * E_ + t * 64
                             + ((slotL ^ (row & 7)) * 4);
            GLOAD_LDS16(src, (char*)&Asf[buf][0][0] + s * 4096 + tid * 16);
        }
    };

    f32x4 acc[3][2][2];
#pragma unroll
    for (int w = 0; w < 3; ++w)
#pragma unroll
        for (int mi = 0; mi < 2; ++mi)
#pragma unroll
            for (int ni = 0; ni < 2; ++ni) acc[w][mi][ni] = (f32x4){0.f, 0.f, 0.f, 0.f};

    // prologue: tiles 0,1 in flight (4 outstanding gloads)
    ASTAGE(0, 0);
    ASTAGE(1, 1);

    for (int t = 0; t < 16; ++t) {
        const int a0 = t % 3;
        // retire A(t) (issued 2 bodies ago); keep A(t+1) (2 loads) in flight
        asm volatile("s_waitcnt vmcnt(2)\n\ts_barrier" ::: "memory");
        __builtin_amdgcn_sched_barrier(0);
        if (t < 15) ASTAGE((t + 2) % 3, min(t + 2, 15));   // 2-ahead (dummy @14)

        // B fragments for tile t (L2-resident, consumed this body)
        bf16x8 bw[3][2][2];   // [w][ks][ni]
        const unsigned short* wp = wbase + (size_t)t * 8192;
#pragma unroll
        for (int w = 0; w < 3; ++w)
#pragma unroll
            for (int ks = 0; ks < 2; ++ks)
#pragma unroll
                for (int ni = 0; ni < 2; ++ni)
                    bw[w][ks][ni] = *(const bf16x8*)(wp + (size_t)w * 131072 + ks * 4096 + ni * 128);

        // A fragments: f32 from LDS + pack2bf conversion
        bf16x8 af[2][2];      // [mi][ks]
#pragma unroll
        for (int mi = 0; mi < 2; ++mi)
#pragma unroll
            for (int ks = 0; ks < 2; ++ks) {
                int row = mi * 16 + lrow;
                int m7 = row & 7;
                int s0 = 2 * (ks * 4 + lq);
                f32x4 f0 = *(const f32x4*)&Asf[a0][row][((s0)     ^ m7) * 4];
                f32x4 f1 = *(const f32x4*)&Asf[a0][row][((s0 + 1) ^ m7) * 4];
                union { unsigned int u[4]; bf16x8 v; } pk;
                pk.u[0] = pack2bf(f0[0], f0[1]);
                pk.u[1] = pack2bf(f0[2], f0[3]);
                pk.u[2] = pack2bf(f1[0], f1[1]);
                pk.u[3] = pack2bf(f1[2], f1[3]);
                af[mi][ks] = pk.v;
            }

        __builtin_amdgcn_s_setprio(1);
#pragma unroll
        for (int ks = 0; ks < 2; ++ks)
#pragma unroll
            for (int w = 0; w < 3; ++w)
#pragma unroll
                for (int ni = 0; ni < 2; ++ni)
#pragma unroll
                    for (int mi = 0; mi < 2; ++mi)
                        acc[w][mi][ni] = MF(af[mi][ks], bw[w][ks][ni], acc[w][mi][ni]);
        __builtin_amdgcn_s_setprio(0);
    }

    // epilogue: Q (scaled 1/32), K row-major; V transposed [b][h][c]
#pragma unroll
    for (int w = 0; w < 2; ++w) {
        const float qs = (w == 0) ? 0.03125f : 1.0f;   // fold 1/sqrt(E) into Q
        unsigned short* outp = QKV + (size_t)w * M_ * H_;
#pragma unroll
        for (int mi = 0; mi < 2; ++mi) {
            int r0 = row0 + mi * 16 + lq * 4;
#pragma unroll
            for (int ni = 0; ni < 2; ++ni) {
                int col = wcol + ni * 16 + lrow;
#pragma unroll
                for (int r = 0; r < 4; ++r)
                    outp[(size_t)(r0 + r) * H_ + col] = f2bf(acc[w][mi][ni][r] * qs);
            }
        }
    }
    {
        unsigned short* vt = QKV + (size_t)2 * M_ * H_;
        int b = row0 / C_;
        int cbase = row0 % C_;
#pragma unroll
        for (int mi = 0; mi < 2; ++mi) {
            int c0 = cbase + mi * 16 + lq * 4;
#pragma unroll
            for (int ni = 0; ni < 2; ++ni) {
                int h = wcol + ni * 16 + lrow;
                __align__(8) unsigned short p[4] = {f2bf(acc[2][mi][ni][0]), f2bf(acc[2][mi][ni][1]),
                                                    f2bf(acc[2][mi][ni][2]), f2bf(acc[2][mi][ni][3])};
                *(uint2*)&vt[((size_t)b * H_ + h) * C_ + c0] = *(const uint2*)p;
            }
        }
    }
}

// ---------------- split-KV flash attention, swapped-QK lane-local softmax ----
// grid (B, 144): blockIdx.x = batch -> XCD = b.
__global__ __launch_bounds__(256) void attn_kernel(const unsigned short* __restrict__ QKV,
                                                   unsigned short* __restrict__ PO,
                                                   float* __restrict__ ML,
                                                   float* __restrict__ out) {
    __shared__ __align__(16) unsigned short Ks[2][64][128];
    __shared__ __align__(16) unsigned short Vt[2][128][64];

    const unsigned short* Q  = QKV;
    const unsigned short* K  = QKV + (size_t)M_ * H_;
    const unsigned short* VT = QKV + (size_t)2 * M_ * H_;

    const int tid = threadIdx.x, wid = tid >> 6, lane = tid & 63;
    const int lrow = lane & 15, lq = lane >> 4, lk = lq * 8;
    const int b = blockIdx.x;
    const int rr = blockIdx.y;

    int j = 0;
#pragma unroll
    for (int jj = 1; jj < 32; ++jj) {
        int q = jj >> 2, s = jj & 3;
        if (jj + 2 * q * (q - 1) + s * q <= rr) j = jj;
    }
    const int qj = j >> 2, sj = j & 3;
    const int Cj = j + 2 * qj * (qj - 1) + sj * qj;
    const int c = rr - Cj;
    const int nch = qj + 1;
    const int t0 = c * 4;
    const int t1 = min(t0 + 4, j + 1);

    const int q0w = j * 64 + wid * 16;
    const unsigned short* Kb  = K  + (size_t)b * C_ * H_;
    const unsigned short* VTb = VT + (size_t)b * H_ * C_;
    const int qabs = q0w + lrow;        // this lane's q row (softmax space)

    const int krow = tid >> 4, kg = tid & 15;
    const int vrow = tid >> 3, vg = tid & 7;

    bf16x8 qf[4];
#pragma unroll
    for (int kf = 0; kf < 4; ++kf)
        qf[kf] = *(const bf16x8*)&Q[((size_t)b * C_ + q0w + lrow) * H_ + kf * 32 + lk];

    f32x4 o[8];
#pragma unroll
    for (int nf = 0; nf < 8; ++nf) o[nf] = (f32x4){0.f, 0.f, 0.f, 0.f};
    float m = -INFINITY, l = 0.f;       // scalar state for q = qabs

    auto STAGE = [&](int buf, int t) {
        const int kv0 = t * 64;
#pragma unroll
        for (int s = 0; s < 4; ++s) {
            int r = s * 16 + krow;      // LDS row
            int prow = ((r & 0x10) << 1) | ((r & 0x0C) << 1) | ((r & 0x20) >> 3) | (r & 3);
            GLOAD_LDS16(&Kb[(size_t)(kv0 + prow) * H_ + ((kg ^ (r & 15)) * 8)],
                        (char*)&Ks[buf][0][0] + s * 4096 + tid * 16);
        }
#pragma unroll
        for (int s = 0; s < 4; ++s) {
            int h = s * 32 + vrow;
            GLOAD_LDS16(&VTb[(size_t)h * C_ + kv0 + ((vg ^ (h & 7)) * 8)],
                        (char*)&Vt[buf][0][0] + s * 4096 + tid * 16);
        }
    };

    STAGE(0, t0);

    for (int t = t0; t < t1; ++t) {
        const int cur = (t - t0) & 1;
        __syncthreads();
        if (t + 1 < t1) STAGE(cur ^ 1, t + 1);

        const int kv0 = t * 64;
        f32x4 s[4];
        __builtin_amdgcn_s_setprio(1);
#pragma unroll
        for (int nf = 0; nf < 4; ++nf) {
            s[nf] = (f32x4){0.f, 0.f, 0.f, 0.f};
            const int rk = nf * 16 + lrow;
#pragma unroll
            for (int kf = 0; kf < 4; ++kf) {
                bf16x8 kb = *(const bf16x8*)&Ks[cur][rk][((kf * 4 + lq) ^ (rk & 15)) * 8];
                s[nf] = __builtin_amdgcn_mfma_f32_16x16x32_bf16(kb, qf[kf], s[nf], 0, 0, 0); // SWAPPED
            }
        }
        __builtin_amdgcn_s_setprio(0);
        bf16x8 vb[8][2];
#pragma unroll
        for (int nf = 0; nf < 8; ++nf) {
            const int h = nf * 16 + lrow;
#pragma unroll
            for (int kf2 = 0; kf2 < 2; ++kf2)
                vb[nf][kf2] = *(const bf16x8*)&Vt[cur][h][((kf2 * 4 + lq) ^ (h & 7)) * 8];
        }

        // lane holds S[kv][q=qabs]; kv = kv0 + (nf&1)*32 + lq*8 + (nf>>1)*4 + r
        if (t == j) {
#pragma unroll
            for (int nf = 0; nf < 4; ++nf) {
                int kvb = kv0 + ((nf & 1) << 5) + (lq << 3) + ((nf >> 1) << 2);
#pragma unroll
                for (int r = 0; r < 4; ++r)
                    if (kvb + r > qabs) s[nf][r] = -INFINITY;
            }
        }
        float mt = s[0][0];
#pragma unroll
        for (int nf = 0; nf < 4; ++nf)
#pragma unroll
            for (int r = 0; r < 4; ++r) mt = fmaxf(mt, s[nf][r]);
        mt = fmaxf(mt, __shfl_xor(mt, 16));
        mt = fmaxf(mt, __shfl_xor(mt, 32));

        float mn = fmaxf(m, mt);
        float corr = __expf(m - mn);
        m = mn;

        float p[4][4];
        float ps = 0.f;
#pragma unroll
        for (int nf = 0; nf < 4; ++nf)
#pragma unroll
            for (int r = 0; r < 4; ++r) {
                float e = __expf(s[nf][r] - mn);
                p[nf][r] = e;
                ps += e;
            }
        ps += __shfl_xor(ps, 16);
        ps += __shfl_xor(ps, 32);
        l = l * corr + ps;

        float corr4[4];
#pragma unroll
        for (int r = 0; r < 4; ++r)
            corr4[r] = __shfl(corr, (lane & 48) | (lq * 4 + r));
#pragma unroll
        for (int nf = 0; nf < 8; ++nf)
#pragma unroll
            for (int r = 0; r < 4; ++r) o[nf][r] *= corr4[r];

        bf16x8 pa[2];
#pragma unroll
        for (int kf2 = 0; kf2 < 2; ++kf2) {
            union { unsigned int u[4]; bf16x8 v; } pk;
            pk.u[0] = pack2bf(p[kf2][0],     p[kf2][1]);
            pk.u[1] = pack2bf(p[kf2][2],     p[kf2][3]);
            pk.u[2] = pack2bf(p[kf2 + 2][0], p[kf2 + 2][1]);
            pk.u[3] = pack2bf(p[kf2 + 2][2], p[kf2 + 2][3]);
            pa[kf2] = pk.v;
        }
        __builtin_amdgcn_s_setprio(1);
#pragma unroll
        for (int nf = 0; nf < 8; ++nf)
#pragma unroll
            for (int kf2 = 0; kf2 < 2; ++kf2)
                o[nf] = __builtin_amdgcn_mfma_f32_16x16x32_bf16(pa[kf2], vb[nf][kf2], o[nf], 0, 0, 0);
        __builtin_amdgcn_s_setprio(0);
    }

    float l4[4], m4[4];
#pragma unroll
    for (int r = 0; r < 4; ++r) {
        l4[r] = __shfl(l, (lane & 48) | (lq * 4 + r));
        m4[r] = __shfl(m, (lane & 48) | (lq * 4 + r));
    }
    const int qrow0 = q0w + lq * 4;

    if (nch == 1) {
#pragma unroll
        for (int nf = 0; nf < 8; ++nf) {
            int col = nf * 16 + lrow;
#pragma unroll
            for (int r = 0; r < 4; ++r)
                out[((size_t)b * C_ + qrow0 + r) * H_ + col] = o[nf][r] / l4[r];
        }
    } else {
        const int slot = b * SLOTS_B + rr;
        unsigned short* po = PO + (size_t)slot * 64 * 128;
        const int rl0 = wid * 16 + lq * 4;
#pragma unroll
        for (int nf = 0; nf < 8; ++nf) {
            int col = nf * 16 + lrow;
#pragma unroll
            for (int r = 0; r < 4; ++r)
                po[(size_t)(rl0 + r) * 128 + col] = f2bf(o[nf][r]);
        }
        if (lrow == 0) {
            float* ml = ML + (size_t)slot * 128;
#pragma unroll
            for (int r = 0; r < 4; ++r) {
                ml[rl0 + r] = m4[r];
                ml[64 + rl0 + r] = l4[r];
            }
        }
    }
}

// ---------------- combine partials for j >= 4 --------------------------------
__global__ __launch_bounds__(256) void combine_kernel(const unsigned short* __restrict__ PO,
                                                      const float* __restrict__ ML,
                                                      float* __restrict__ out) {
    const int j = blockIdx.x + 4;
    const int b = blockIdx.y;
    const int q = j >> 2, s = j & 3;
    const int Cj = j + 2 * q * (q - 1) + s * q;
    const int nch = q + 1;
    const int base = b * SLOTS_B + Cj;
    const int row = threadIdx.x >> 2;
    const int colg = (threadIdx.x & 3) * 32;

    float mstar = -INFINITY;
    for (int c = 0; c < nch; ++c)
        mstar = fmaxf(mstar, ML[(size_t)(base + c) * 128 + row]);

    float denom = 0.f;
    float acc[32];
#pragma unroll
    for (int i = 0; i < 32; ++i) acc[i] = 0.f;

    for (int c = 0; c < nch; ++c) {
        float mc = ML[(size_t)(base + c) * 128 + row];
        float lc = ML[(size_t)(base + c) * 128 + 64 + row];
        float w = __expf(mc - mstar);
        denom += w * lc;
        const unsigned short* p = PO + (size_t)(base + c) * 64 * 128 + (size_t)row * 128 + colg;
#pragma unroll
        for (int k = 0; k < 4; ++k) {
            bf16x8 v = *(const bf16x8*)&p[k * 8];
#pragma unroll
            for (int e = 0; e < 8; ++e)
                acc[k * 8 + e] += w * bf2f(((unsigned short*)&v)[e]);
        }
    }
    float inv = 1.f / denom;
    float* op = out + ((size_t)b * C_ + j * 64 + row) * H_ + colg;
#pragma unroll
    for (int k = 0; k < 8; ++k) {
        float4 st = {acc[k * 4] * inv, acc[k * 4 + 1] * inv, acc[k * 4 + 2] * inv, acc[k * 4 + 3] * inv};
        *(float4*)&op[k * 4] = st;
    }
}

extern "C" void kernel_launch(void* const* d_in, const int* in_sizes, int n_in,
                              void* d_out, int out_size, void* d_ws, size_t ws_size,
                              hipStream_t stream) {
    const float* x  = (const float*)d_in[0];
    const float* Wq = (const float*)d_in[1];
    const float* Wk = (const float*)d_in[2];
    const float* Wv = (const float*)d_in[3];
    float* out = (float*)d_out;

    unsigned short* WT2 = (unsigned short*)d_ws;                       // 768 KB
    unsigned short* QKV = WT2 + (size_t)3 * H_ * E_;                   // 12 MB (Q, K, V^T)
    unsigned short* PO  = QKV + (size_t)3 * M_ * H_;                   // 18 MB partial O
    float*          ML  = (float*)(PO + (size_t)8 * SLOTS_B * 64 * 128); // 576 KB m,l

    wt2_kernel<<<dim3(E_ / 8 * H_ / 256, 3), 256, 0, stream>>>(Wq, Wk, Wv, WT2);
    proj_kernel<<<dim3(M_ / 32), 256, 0, stream>>>(x, WT2, QKV);
    attn_kernel<<<dim3(B_, SLOTS_B), 256, 0, stream>>>(QKV, PO, ML, out);
    combine_kernel<<<dim3(28, B_), 256, 0, stream>>>(PO, ML, out);
}

// Round 16
// 71.018 us; speedup vs baseline: 1.2955x; 1.0136x over previous
//
#include <hip/hip_runtime.h>
#include <hip/hip_bf16.h>
#include <stdint.h>

#define B_ 8
#define C_ 2048
#define E_ 1024
#define H_ 128
#define M_ (B_*C_)      // 16384 rows total
#define SLOTS_B 144     // chunks per batch: sum_j ceil((j+1)/4), j<32

typedef __attribute__((ext_vector_type(8))) short bf16x8;
typedef __attribute__((ext_vector_type(4))) float f32x4;

__device__ __forceinline__ unsigned short f2bf(float f) {
    union { float f; unsigned int u; } v; v.f = f;
    unsigned int u = v.u;
    u += 0x7fff + ((u >> 16) & 1);   // RNE
    return (unsigned short)(u >> 16);
}
__device__ __forceinline__ float bf2f(unsigned short u) {
    union { unsigned int i; float f; } v; v.i = ((unsigned int)u) << 16; return v.f;
}
// pack two floats -> two bf16 (round-half-up) in ONE v_perm + 2 adds
__device__ __forceinline__ unsigned int pack2bf(float lo, float hi) {
    union { float f; unsigned int u; } a, b; a.f = lo; b.f = hi;
    return __builtin_amdgcn_perm(b.u + 0x8000u, a.u + 0x8000u, 0x07060302);
}

#define GLOAD_LDS16(g, l) \
    __builtin_amdgcn_global_load_lds((const __attribute__((address_space(1))) void*)(g), \
                                     (__attribute__((address_space(3))) void*)(l), 16, 0, 0)

// -------- W -> wave-contiguous fragment layout WT3 --------------------------
// granule index g = ((((t*2+ks)*4+wid)*2+ni)*4+lq)*16 + lrow   (16384 per w)
// granule content: W[k..k+7][h], k = t*64+ks*32+lq*8, h = wid*32+ni*16+lrow.
// A wave's per-instruction load (fixed t,ks,wid,ni) spans lanes (lq,lrow)
// = 64 consecutive granules = ONE contiguous 1KB segment.
__global__ __launch_bounds__(256) void wt3_kernel(const float* __restrict__ Wq,
                                                  const float* __restrict__ Wk,
                                                  const float* __restrict__ Wv,
                                                  unsigned short* __restrict__ WT3) {
    int z = blockIdx.y;
    const float* W = (z == 0) ? Wq : (z == 1) ? Wk : Wv;
    unsigned short* o = WT3 + (size_t)z * H_ * E_;
    int g = blockIdx.x * 256 + threadIdx.x;     // granule id, 0..16383
    int lrow = g & 15;
    int lq   = (g >> 4) & 3;
    int ni   = (g >> 6) & 1;
    int wid  = (g >> 7) & 3;
    int ks   = (g >> 9) & 1;
    int t    = g >> 10;
    int k = t * 64 + ks * 32 + lq * 8;
    int h = wid * 32 + ni * 16 + lrow;
    unsigned short v[8];
#pragma unroll
    for (int j = 0; j < 8; ++j)
        v[j] = f2bf(W[(size_t)(k + j) * H_ + h]);
    *(bf16x8*)&o[(size_t)g * 8] = *(const bf16x8*)v;
}

// ------ fused QKV projection: BM=32, x once; A f32 gload_lds 3-buf 2-ahead
// counted vmcnt(2); B direct global->reg from WT3 (1KB-contiguous loads).
#define MF(a, b, c) __builtin_amdgcn_mfma_f32_16x16x32_bf16((a), (b), (c), 0, 0, 0)

__global__ __launch_bounds__(256) void proj_kernel(const float* __restrict__ x,
                                                   const unsigned short* __restrict__ WT3,
                                                   unsigned short* __restrict__ QKV) {
    __shared__ __align__(16) float Asf[3][32][64];    // 24 KB, 16B-slot XOR-swz

    const int tid = threadIdx.x;
    const int wid = tid >> 6, lane = tid & 63;
    const int lrow = lane & 15, lq = lane >> 4;
    const int wcol = wid * 32;          // wave's 32-col slice of H=128
    const int row0 = blockIdx.x * 32;
    // per-lane base into WT3: wid-slice + lane*8 (= lq*128 + lrow*8 shorts)
    const unsigned short* wbase = WT3 + (size_t)wid * 1024 + (size_t)lane * 8;

    // A staging: 8 KB/tile = 2 shots x 256 thr x 16B; exactly 2 gloads/thread
    const int srow = tid >> 4;          // row within shot (0..15)
    const int slotL = tid & 15;         // linear LDS 16B-slot

    auto ASTAGE = [&](int buf, int t) {
#pragma unroll
        for (int s = 0; s < 2; ++s) {
            int row = s * 16 + srow;
            const float* src = x + (size_t)(row0 + row) * E_ + t * 64
                             + ((slotL ^ (row & 7)) * 4);
            GLOAD_LDS16(src, (char*)&Asf[buf][0][0] + s * 4096 + tid * 16);
        }
    };

    f32x4 acc[3][2][2];
#pragma unroll
    for (int w = 0; w < 3; ++w)
#pragma unroll
        for (int mi = 0; mi < 2; ++mi)
#pragma unroll
            for (int ni = 0; ni < 2; ++ni) acc[w][mi][ni] = (f32x4){0.f, 0.f, 0.f, 0.f};

    // prologue: tiles 0,1 in flight (4 outstanding gloads)
    ASTAGE(0, 0);
    ASTAGE(1, 1);

    for (int t = 0; t < 16; ++t) {
        const int a0 = t % 3;
        // retire A(t) (issued 2 bodies ago); keep A(t+1) (2 loads) in flight
        asm volatile("s_waitcnt vmcnt(2)\n\ts_barrier" ::: "memory");
        __builtin_amdgcn_sched_barrier(0);
        if (t < 15) ASTAGE((t + 2) % 3, min(t + 2, 15));   // 2-ahead (dummy @14)

        // B fragments for tile t: each load = 1KB contiguous (L2-friendly)
        // strides (shorts): w 131072, t 8192, ks 4096, ni 512
        bf16x8 bw[3][2][2];   // [w][ks][ni]
        const unsigned short* wp = wbase + (size_t)t * 8192;
#pragma unroll
        for (int w = 0; w < 3; ++w)
#pragma unroll
            for (int ks = 0; ks < 2; ++ks)
#pragma unroll
                for (int ni = 0; ni < 2; ++ni)
                    bw[w][ks][ni] = *(const bf16x8*)(wp + (size_t)w * 131072 + ks * 4096 + ni * 512);

        // A fragments: f32 from LDS + pack2bf conversion
        bf16x8 af[2][2];      // [mi][ks]
#pragma unroll
        for (int mi = 0; mi < 2; ++mi)
#pragma unroll
            for (int ks = 0; ks < 2; ++ks) {
                int row = mi * 16 + lrow;
                int m7 = row & 7;
                int s0 = 2 * (ks * 4 + lq);
                f32x4 f0 = *(const f32x4*)&Asf[a0][row][((s0)     ^ m7) * 4];
                f32x4 f1 = *(const f32x4*)&Asf[a0][row][((s0 + 1) ^ m7) * 4];
                union { unsigned int u[4]; bf16x8 v; } pk;
                pk.u[0] = pack2bf(f0[0], f0[1]);
                pk.u[1] = pack2bf(f0[2], f0[3]);
                pk.u[2] = pack2bf(f1[0], f1[1]);
                pk.u[3] = pack2bf(f1[2], f1[3]);
                af[mi][ks] = pk.v;
            }

        __builtin_amdgcn_s_setprio(1);
#pragma unroll
        for (int ks = 0; ks < 2; ++ks)
#pragma unroll
            for (int w = 0; w < 3; ++w)
#pragma unroll
                for (int ni = 0; ni < 2; ++ni)
#pragma unroll
                    for (int mi = 0; mi < 2; ++mi)
                        acc[w][mi][ni] = MF(af[mi][ks], bw[w][ks][ni], acc[w][mi][ni]);
        __builtin_amdgcn_s_setprio(0);
    }

    // epilogue: Q (scaled 1/32), K row-major; V transposed [b][h][c]
#pragma unroll
    for (int w = 0; w < 2; ++w) {
        const float qs = (w == 0) ? 0.03125f : 1.0f;   // fold 1/sqrt(E) into Q
        unsigned short* outp = QKV + (size_t)w * M_ * H_;
#pragma unroll
        for (int mi = 0; mi < 2; ++mi) {
            int r0 = row0 + mi * 16 + lq * 4;
#pragma unroll
            for (int ni = 0; ni < 2; ++ni) {
                int col = wcol + ni * 16 + lrow;
#pragma unroll
                for (int r = 0; r < 4; ++r)
                    outp[(size_t)(r0 + r) * H_ + col] = f2bf(acc[w][mi][ni][r] * qs);
            }
        }
    }
    {
        unsigned short* vt = QKV + (size_t)2 * M_ * H_;
        int b = row0 / C_;
        int cbase = row0 % C_;
#pragma unroll
        for (int mi = 0; mi < 2; ++mi) {
            int c0 = cbase + mi * 16 + lq * 4;
#pragma unroll
            for (int ni = 0; ni < 2; ++ni) {
                int h = wcol + ni * 16 + lrow;
                __align__(8) unsigned short p[4] = {f2bf(acc[2][mi][ni][0]), f2bf(acc[2][mi][ni][1]),
                                                    f2bf(acc[2][mi][ni][2]), f2bf(acc[2][mi][ni][3])};
                *(uint2*)&vt[((size_t)b * H_ + h) * C_ + c0] = *(const uint2*)p;
            }
        }
    }
}

// ---------------- split-KV flash attention, swapped-QK lane-local softmax ----
// grid (B, 144): blockIdx.x = batch -> XCD = b.
__global__ __launch_bounds__(256) void attn_kernel(const unsigned short* __restrict__ QKV,
                                                   unsigned short* __restrict__ PO,
                                                   float* __restrict__ ML,
                                                   float* __restrict__ out) {
    __shared__ __align__(16) unsigned short Ks[2][64][128];
    __shared__ __align__(16) unsigned short Vt[2][128][64];

    const unsigned short* Q  = QKV;
    const unsigned short* K  = QKV + (size_t)M_ * H_;
    const unsigned short* VT = QKV + (size_t)2 * M_ * H_;

    const int tid = threadIdx.x, wid = tid >> 6, lane = tid & 63;
    const int lrow = lane & 15, lq = lane >> 4, lk = lq * 8;
    const int b = blockIdx.x;
    const int rr = blockIdx.y;

    int j = 0;
#pragma unroll
    for (int jj = 1; jj < 32; ++jj) {
        int q = jj >> 2, s = jj & 3;
        if (jj + 2 * q * (q - 1) + s * q <= rr) j = jj;
    }
    const int qj = j >> 2, sj = j & 3;
    const int Cj = j + 2 * qj * (qj - 1) + sj * qj;
    const int c = rr - Cj;
    const int nch = qj + 1;
    const int t0 = c * 4;
    const int t1 = min(t0 + 4, j + 1);

    const int q0w = j * 64 + wid * 16;
    const unsigned short* Kb  = K  + (size_t)b * C_ * H_;
    const unsigned short* VTb = VT + (size_t)b * H_ * C_;
    const int qabs = q0w + lrow;        // this lane's q row (softmax space)

    const int krow = tid >> 4, kg = tid & 15;
    const int vrow = tid >> 3, vg = tid & 7;

    bf16x8 qf[4];
#pragma unroll
    for (int kf = 0; kf < 4; ++kf)
        qf[kf] = *(const bf16x8*)&Q[((size_t)b * C_ + q0w + lrow) * H_ + kf * 32 + lk];

    f32x4 o[8];
#pragma unroll
    for (int nf = 0; nf < 8; ++nf) o[nf] = (f32x4){0.f, 0.f, 0.f, 0.f};
    float m = -INFINITY, l = 0.f;       // scalar state for q = qabs

    auto STAGE = [&](int buf, int t) {
        const int kv0 = t * 64;
#pragma unroll
        for (int s = 0; s < 4; ++s) {
            int r = s * 16 + krow;      // LDS row
            int prow = ((r & 0x10) << 1) | ((r & 0x0C) << 1) | ((r & 0x20) >> 3) | (r & 3);
            GLOAD_LDS16(&Kb[(size_t)(kv0 + prow) * H_ + ((kg ^ (r & 15)) * 8)],
                        (char*)&Ks[buf][0][0] + s * 4096 + tid * 16);
        }
#pragma unroll
        for (int s = 0; s < 4; ++s) {
            int h = s * 32 + vrow;
            GLOAD_LDS16(&VTb[(size_t)h * C_ + kv0 + ((vg ^ (h & 7)) * 8)],
                        (char*)&Vt[buf][0][0] + s * 4096 + tid * 16);
        }
    };

    STAGE(0, t0);

    for (int t = t0; t < t1; ++t) {
        const int cur = (t - t0) & 1;
        __syncthreads();
        if (t + 1 < t1) STAGE(cur ^ 1, t + 1);

        const int kv0 = t * 64;
        f32x4 s[4];
        __builtin_amdgcn_s_setprio(1);
#pragma unroll
        for (int nf = 0; nf < 4; ++nf) {
            s[nf] = (f32x4){0.f, 0.f, 0.f, 0.f};
            const int rk = nf * 16 + lrow;
#pragma unroll
            for (int kf = 0; kf < 4; ++kf) {
                bf16x8 kb = *(const bf16x8*)&Ks[cur][rk][((kf * 4 + lq) ^ (rk & 15)) * 8];
                s[nf] = __builtin_amdgcn_mfma_f32_16x16x32_bf16(kb, qf[kf], s[nf], 0, 0, 0); // SWAPPED
            }
        }
        __builtin_amdgcn_s_setprio(0);
        bf16x8 vb[8][2];
#pragma unroll
        for (int nf = 0; nf < 8; ++nf) {
            const int h = nf * 16 + lrow;
#pragma unroll
            for (int kf2 = 0; kf2 < 2; ++kf2)
                vb[nf][kf2] = *(const bf16x8*)&Vt[cur][h][((kf2 * 4 + lq) ^ (h & 7)) * 8];
        }

        // lane holds S[kv][q=qabs]; kv = kv0 + (nf&1)*32 + lq*8 + (nf>>1)*4 + r
        if (t == j) {
#pragma unroll
            for (int nf = 0; nf < 4; ++nf) {
                int kvb = kv0 + ((nf & 1) << 5) + (lq << 3) + ((nf >> 1) << 2);
#pragma unroll
                for (int r = 0; r < 4; ++r)
                    if (kvb + r > qabs) s[nf][r] = -INFINITY;
            }
        }
        float mt = s[0][0];
#pragma unroll
        for (int nf = 0; nf < 4; ++nf)
#pragma unroll
            for (int r = 0; r < 4; ++r) mt = fmaxf(mt, s[nf][r]);
        mt = fmaxf(mt, __shfl_xor(mt, 16));
        mt = fmaxf(mt, __shfl_xor(mt, 32));

        float mn = fmaxf(m, mt);
        float corr = __expf(m - mn);
        m = mn;

        float p[4][4];
        float ps = 0.f;
#pragma unroll
        for (int nf = 0; nf < 4; ++nf)
#pragma unroll
            for (int r = 0; r < 4; ++r) {
                float e = __expf(s[nf][r] - mn);
                p[nf][r] = e;
                ps += e;
            }
        ps += __shfl_xor(ps, 16);
        ps += __shfl_xor(ps, 32);
        l = l * corr + ps;

        float corr4[4];
#pragma unroll
        for (int r = 0; r < 4; ++r)
            corr4[r] = __shfl(corr, (lane & 48) | (lq * 4 + r));
#pragma unroll
        for (int nf = 0; nf < 8; ++nf)
#pragma unroll
            for (int r = 0; r < 4; ++r) o[nf][r] *= corr4[r];

        bf16x8 pa[2];
#pragma unroll
        for (int kf2 = 0; kf2 < 2; ++kf2) {
            union { unsigned int u[4]; bf16x8 v; } pk;
            pk.u[0] = pack2bf(p[kf2][0],     p[kf2][1]);
            pk.u[1] = pack2bf(p[kf2][2],     p[kf2][3]);
            pk.u[2] = pack2bf(p[kf2 + 2][0], p[kf2 + 2][1]);
            pk.u[3] = pack2bf(p[kf2 + 2][2], p[kf2 + 2][3]);
            pa[kf2] = pk.v;
        }
        __builtin_amdgcn_s_setprio(1);
#pragma unroll
        for (int nf = 0; nf < 8; ++nf)
#pragma unroll
            for (int kf2 = 0; kf2 < 2; ++kf2)
                o[nf] = __builtin_amdgcn_mfma_f32_16x16x32_bf16(pa[kf2], vb[nf][kf2], o[nf], 0, 0, 0);
        __builtin_amdgcn_s_setprio(0);
    }

    float l4[4], m4[4];
#pragma unroll
    for (int r = 0; r < 4; ++r) {
        l4[r] = __shfl(l, (lane & 48) | (lq * 4 + r));
        m4[r] = __shfl(m, (lane & 48) | (lq * 4 + r));
    }
    const int qrow0 = q0w + lq * 4;

    if (nch == 1) {
#pragma unroll
        for (int nf = 0; nf < 8; ++nf) {
            int col = nf * 16 + lrow;
#pragma unroll
            for (int r = 0; r < 4; ++r)
                out[((size_t)b * C_ + qrow0 + r) * H_ + col] = o[nf][r] / l4[r];
        }
    } else {
        const int slot = b * SLOTS_B + rr;
        unsigned short* po = PO + (size_t)slot * 64 * 128;
        const int rl0 = wid * 16 + lq * 4;
#pragma unroll
        for (int nf = 0; nf < 8; ++nf) {
            int col = nf * 16 + lrow;
#pragma unroll
            for (int r = 0; r < 4; ++r)
                po[(size_t)(rl0 + r) * 128 + col] = f2bf(o[nf][r]);
        }
        if (lrow == 0) {
            float* ml = ML + (size_t)slot * 128;
#pragma unroll
            for (int r = 0; r < 4; ++r) {
                ml[rl0 + r] = m4[r];
                ml[64 + rl0 + r] = l4[r];
            }
        }
    }
}

// ---------------- combine partials for j >= 4 --------------------------------
__global__ __launch_bounds__(256) void combine_kernel(const unsigned short* __restrict__ PO,
                                                      const float* __restrict__ ML,
                                                      float* __restrict__ out) {
    const int j = blockIdx.x + 4;
    const int b = blockIdx.y;
    const int q = j >> 2, s = j & 3;
    const int Cj = j + 2 * q * (q - 1) + s * q;
    const int nch = q + 1;
    const int base = b * SLOTS_B + Cj;
    const int row = threadIdx.x >> 2;
    const int colg = (threadIdx.x & 3) * 32;

    float mstar = -INFINITY;
    for (int c = 0; c < nch; ++c)
        mstar = fmaxf(mstar, ML[(size_t)(base + c) * 128 + row]);

    float denom = 0.f;
    float acc[32];
#pragma unroll
    for (int i = 0; i < 32; ++i) acc[i] = 0.f;

    for (int c = 0; c < nch; ++c) {
        float mc = ML[(size_t)(base + c) * 128 + row];
        float lc = ML[(size_t)(base + c) * 128 + 64 + row];
        float w = __expf(mc - mstar);
        denom += w * lc;
        const unsigned short* p = PO + (size_t)(base + c) * 64 * 128 + (size_t)row * 128 + colg;
#pragma unroll
        for (int k = 0; k < 4; ++k) {
            bf16x8 v = *(const bf16x8*)&p[k * 8];
#pragma unroll
            for (int e = 0; e < 8; ++e)
                acc[k * 8 + e] += w * bf2f(((unsigned short*)&v)[e]);
        }
    }
    float inv = 1.f / denom;
    float* op = out + ((size_t)b * C_ + j * 64 + row) * H_ + colg;
#pragma unroll
    for (int k = 0; k < 8; ++k) {
        float4 st = {acc[k * 4] * inv, acc[k * 4 + 1] * inv, acc[k * 4 + 2] * inv, acc[k * 4 + 3] * inv};
        *(float4*)&op[k * 4] = st;
    }
}

extern "C" void kernel_launch(void* const* d_in, const int* in_sizes, int n_in,
                              void* d_out, int out_size, void* d_ws, size_t ws_size,
                              hipStream_t stream) {
    const float* x  = (const float*)d_in[0];
    const float* Wq = (const float*)d_in[1];
    const float* Wk = (const float*)d_in[2];
    const float* Wv = (const float*)d_in[3];
    float* out = (float*)d_out;

    unsigned short* WT3 = (unsigned short*)d_ws;                       // 768 KB
    unsigned short* QKV = WT3 + (size_t)3 * H_ * E_;                   // 12 MB (Q, K, V^T)
    unsigned short* PO  = QKV + (size_t)3 * M_ * H_;                   // 18 MB partial O
    float*          ML  = (float*)(PO + (size_t)8 * SLOTS_B * 64 * 128); // 576 KB m,l

    wt3_kernel<<<dim3(64, 3), 256, 0, stream>>>(Wq, Wk, Wv, WT3);
    proj_kernel<<<dim3(M_ / 32), 256, 0, stream>>>(x, WT3, QKV);
    attn_kernel<<<dim3(B_, SLOTS_B), 256, 0, stream>>>(QKV, PO, ML, out);
    combine_kernel<<<dim3(28, B_), 256, 0, stream>>>(PO, ML, out);
}